// Round 5
// baseline (294.477 us; speedup 1.0000x reference)
//
#include <hip/hip_runtime.h>
#include <stdint.h>

typedef unsigned short u16;
typedef unsigned int   u32;
typedef __attribute__((ext_vector_type(8))) short bf16x8;
typedef __attribute__((ext_vector_type(4))) float f32x4;

#define EPS 1e-3f
#define NB 32
#define HW 56
#define CI 256
#define CM 128
#define PIX (NB*HW*HW)   // 100352

__device__ __forceinline__ float asf(u32 i){ union{u32 u; float f;} t; t.u=i; return t.f; }
__device__ __forceinline__ u16 f2bf(float f){
  union{float f; u32 u;} t; t.f = f;
  u32 x = t.u;
  return (u16)((x + 0x7fffu + ((x>>16)&1u)) >> 16);   // RNE
}

// ---------------- prep: bf16 transposed weights + BN fold ----------------
// w1 [k=256][n=128] -> w1t bf16 [n=128][k=256]; w3 [k=128][n=256] -> w3t bf16 [n=256][k=128]
__global__ __launch_bounds__(256) void kprep(
    const float* __restrict__ w1, const float* __restrict__ b1, const float* __restrict__ g1,
    const float* __restrict__ be1, const float* __restrict__ m1, const float* __restrict__ v1,
    const float* __restrict__ b2, const float* __restrict__ g2,
    const float* __restrict__ be2, const float* __restrict__ m2, const float* __restrict__ v2,
    const float* __restrict__ w3,
    u16* __restrict__ w1t, u16* __restrict__ w3t,
    float* __restrict__ A1, float* __restrict__ B1,
    float* __restrict__ A2, float* __restrict__ B2){
  int i = blockIdx.x*256 + threadIdx.x;
  if (i < 32768){
    { int n = i >> 8, k = i & 255; w1t[i] = f2bf(w1[k*CM + n]); }
    { int n = i >> 7, k = i & 127; w3t[i] = f2bf(w3[k*CI + n]); }
  }
  if (i < 128){
    float s1 = g1[i] * rsqrtf(v1[i] + EPS);
    A1[i] = s1;
    B1[i] = b1[i]*s1 + be1[i] - m1[i]*s1;
    float s2 = g2[i] * rsqrtf(v2[i] + EPS);
    A2[i] = s2;
    B2[i] = b2[i]*s2 + be2[i] - m2[i]*s2;
  }
}

// ---------------- conv1 1x1 256->128 + BN + ReLU (MFMA bf16) ----------------
// block 256 thr (4 waves). Tile M=128 pixels, N=128 (full), K chunks of 64.
// Wave w: n in [w*32, w*32+32), m in [0,128) (8 m-tiles).
#define K1_LS 72   // LDS row stride (u16): 144 B, 16B-aligned rows
__global__ __launch_bounds__(256) void k1(const float* __restrict__ x,
    const u16* __restrict__ w1t, const float* __restrict__ A1v,
    const float* __restrict__ B1v, u16* __restrict__ h1){
  __shared__ __align__(16) char smem[128*K1_LS*2 * 2];  // A 18432 + B 18432
  u16* As = (u16*)smem;                     // [128][72]
  u16* Bs = (u16*)(smem + 128*K1_LS*2);     // [128][72]
  const int tid  = threadIdx.x;
  const int lane = tid & 63, wv = tid >> 6;
  const int col  = lane & 15, quad = lane >> 4;
  const long p0 = (long)blockIdx.x * 128;
  f32x4 acc[8][2];
  #pragma unroll
  for (int a = 0; a < 8; a++)
    #pragma unroll
    for (int b = 0; b < 2; b++){ acc[a][b][0]=0.f; acc[a][b][1]=0.f; acc[a][b][2]=0.f; acc[a][b][3]=0.f; }
  for (int kc = 0; kc < 4; kc++){
    // stage A: x fp32 -> bf16, 128 rows x 64 k
    #pragma unroll
    for (int r = 0; r < 8; r++){
      int idx = r*256 + tid;
      int m = idx >> 4, f4 = idx & 15;
      float4 v = *(const float4*)(x + (p0+m)*CI + kc*64 + f4*4);
      u32 lo = (u32)f2bf(v.x) | ((u32)f2bf(v.y) << 16);
      u32 hi = (u32)f2bf(v.z) | ((u32)f2bf(v.w) << 16);
      *(uint2*)(As + m*K1_LS + f4*4) = make_uint2(lo, hi);
    }
    // stage B: w1t bf16, 128 rows x 64 k
    #pragma unroll
    for (int r = 0; r < 4; r++){
      int idx = r*256 + tid;
      int n = idx >> 3, u4 = idx & 7;
      uint4 v = *(const uint4*)(w1t + n*CI + kc*64 + u4*8);
      *(uint4*)(Bs + n*K1_LS + u4*8) = v;
    }
    __syncthreads();
    #pragma unroll
    for (int ks = 0; ks < 2; ks++){
      bf16x8 af[8], bfr[2];
      #pragma unroll
      for (int nt = 0; nt < 2; nt++)
        bfr[nt] = *(const bf16x8*)(Bs + (wv*32 + nt*16 + col)*K1_LS + ks*32 + quad*8);
      #pragma unroll
      for (int mt = 0; mt < 8; mt++)
        af[mt] = *(const bf16x8*)(As + (mt*16 + col)*K1_LS + ks*32 + quad*8);
      #pragma unroll
      for (int mt = 0; mt < 8; mt++)
        #pragma unroll
        for (int nt = 0; nt < 2; nt++)
          acc[mt][nt] = __builtin_amdgcn_mfma_f32_16x16x32_bf16(af[mt], bfr[nt], acc[mt][nt], 0, 0, 0);
    }
    __syncthreads();
  }
  // epilogue: BN + ReLU -> bf16, repack via LDS, vector store
  u16* outw = (u16*)smem;   // [128][136] = 34816 B
  #pragma unroll
  for (int nt = 0; nt < 2; nt++){
    int n = wv*32 + nt*16 + col;
    float a1 = A1v[n], b1v = B1v[n];
    #pragma unroll
    for (int mt = 0; mt < 8; mt++)
      #pragma unroll
      for (int reg = 0; reg < 4; reg++){
        int m = mt*16 + quad*4 + reg;
        outw[m*136 + n] = f2bf(fmaxf(acc[mt][nt][reg]*a1 + b1v, 0.f));
      }
  }
  __syncthreads();
  #pragma unroll
  for (int r = 0; r < 8; r++){
    int idx = r*256 + tid;
    int m = idx >> 4, u4 = idx & 15;
    uint4 v = *(const uint4*)(outw + m*136 + u4*8);
    *(uint4*)(h1 + (p0+m)*CM + u4*8) = v;
  }
}

// ---------------- fused: grouped 3x3 + BN + ReLU + conv3 + bias + residual + ReLU ----------------
// 512 thr (8 waves), one block per 2-output-row band. h2 lives only in LDS.
#define LSH1 132   // h1 tile stride (u16): 264 B, 8B-aligned (uint2 ok)
#define LSH2 136   // h2 tile stride (u16): 272 B, 16B-aligned (b128 ok)
__global__ __launch_bounds__(512) void k23(const u16* __restrict__ h1,
    const float* __restrict__ w2, const float* __restrict__ A2v,
    const float* __restrict__ B2v, const u16* __restrict__ w3t,
    const float* __restrict__ b3, const float* __restrict__ x,
    float* __restrict__ out){
  // regions: tile/pre 59136 | h2t 30464 | wsh 18432  => 108032 B
  __shared__ __align__(16) char smem[59136 + 112*LSH2*2 + 4608*4];
  u16*  tile = (u16*)smem;                           // [4][56][132] bf16 h1 band
  u16*  h2t  = (u16*)(smem + 59136);                 // [112][136] bf16 h2 band
  float* wsh = (float*)(smem + 59136 + 112*LSH2*2);  // [4608] fp32 w2
  float* pre = (float*)smem;                         // [112][132] f32 (reuses tile)

  const int tid = threadIdx.x;
  const int g0 = blockIdx.x * 2;          // first output row (global row index)
  const int y0 = g0 % HW;                 // row within image (bands never cross images)
  const long p0 = (long)g0 * HW;          // first output pixel

  // ---- phase A: stage h1 rows y0-1..y0+2 (zero outside image) + w2 ----
  for (int i = tid; i < 1152; i += 512)
    ((float4*)wsh)[i] = ((const float4*)w2)[i];
  #pragma unroll
  for (int r = 0; r < 4; r++){
    const int yy = y0 + r - 1;
    const bool valid = (yy >= 0 && yy < HW);
    const uint4* src = (const uint4*)(h1 + (long)(g0 - y0 + yy)*HW*CM);
    for (int i = tid; i < 896; i += 512){
      uint4 v = make_uint4(0u,0u,0u,0u);
      if (valid) v = src[i];
      int px = i >> 4, ch = (i & 15)*8;
      u16* d = tile + (r*HW + px)*LSH1 + ch;
      *(uint2*)d     = make_uint2(v.x, v.y);
      *(uint2*)(d+4) = make_uint2(v.z, v.w);
    }
  }
  __syncthreads();

  // ---- phase B: grouped 3x3 conv, fp32 VALU, h2 -> LDS ----
  {
    const int q   = tid >> 7;     // channel-quarter 0..3 (wave-uniform)
    const int pos = tid & 127;    // band pixel 0..127, valid < 112
    if (pos < 112){
      const int r_out = (pos >= HW) ? 1 : 0;
      const int px = pos - r_out*HW;
      int ixo[3]; u32 mk[3];
      #pragma unroll
      for (int kx = 0; kx < 3; kx++){
        int c = px + kx - 1;
        ixo[kx] = (c < 0 ? 0 : (c > 55 ? 55 : c)) * LSH1;
        mk[kx] = (c >= 0 && c < HW) ? 0xffffffffu : 0u;
      }
      float acc[8][4];
      #pragma unroll
      for (int gi = 0; gi < 8; gi++){
        const int cb = (q*8 + gi)*4;
        float a0=0.f, a1=0.f, a2=0.f, a3=0.f;
        #pragma unroll
        for (int ky = 0; ky < 3; ky++){
          const u16* trow = tile + (r_out+ky)*HW*LSH1 + cb;
          #pragma unroll
          for (int kx = 0; kx < 3; kx++){
            uint2 hv = *(const uint2*)(trow + ixo[kx]);
            u32 hx = hv.x & mk[kx], hy = hv.y & mk[kx];
            float i0 = asf(hx<<16), i1 = asf(hx&0xffff0000u);
            float i2 = asf(hy<<16), i3 = asf(hy&0xffff0000u);
            const float* wp = wsh + ((ky*3+kx)*4)*CM + cb;   // wave-uniform -> broadcast
            float4 w0 = *(const float4*)(wp);
            float4 w1 = *(const float4*)(wp+CM);
            float4 wq2 = *(const float4*)(wp+2*CM);
            float4 wq3 = *(const float4*)(wp+3*CM);
            a0 += i0*w0.x + i1*w1.x + i2*wq2.x + i3*wq3.x;
            a1 += i0*w0.y + i1*w1.y + i2*wq2.y + i3*wq3.y;
            a2 += i0*w0.z + i1*w1.z + i2*wq2.z + i3*wq3.z;
            a3 += i0*w0.w + i1*w1.w + i2*wq2.w + i3*wq3.w;
          }
        }
        acc[gi][0]=a0; acc[gi][1]=a1; acc[gi][2]=a2; acc[gi][3]=a3;
      }
      u16 ov[32];
      #pragma unroll
      for (int gi = 0; gi < 8; gi++)
        #pragma unroll
        for (int co = 0; co < 4; co++){
          int c = q*32 + gi*4 + co;
          ov[gi*4+co] = f2bf(fmaxf(acc[gi][co]*A2v[c] + B2v[c], 0.f));
        }
      u16* op = h2t + pos*LSH2 + q*32;
      #pragma unroll
      for (int v4 = 0; v4 < 4; v4++){
        uint4 pk;
        pk.x = (u32)ov[v4*8+0] | ((u32)ov[v4*8+1]<<16);
        pk.y = (u32)ov[v4*8+2] | ((u32)ov[v4*8+3]<<16);
        pk.z = (u32)ov[v4*8+4] | ((u32)ov[v4*8+5]<<16);
        pk.w = (u32)ov[v4*8+6] | ((u32)ov[v4*8+7]<<16);
        *(uint4*)(op + v4*8) = pk;
      }
    }
  }
  __syncthreads();

  // ---- phase C: conv3 MFMA. M=112 (7 m-tiles), N=256 (8 waves x 32) ----
  const int lane = tid & 63, wv = tid >> 6;
  const int col  = lane & 15, quad = lane >> 4;
  const int nb = (wv & 3) * 32;   // n base within half
  const int nh = wv >> 2;         // which n-half this wave owns
  const int ng = nh*128 + nb;     // global n base
  f32x4 acc3[7][2];
  #pragma unroll
  for (int a = 0; a < 7; a++)
    #pragma unroll
    for (int b = 0; b < 2; b++){ acc3[a][b][0]=0.f; acc3[a][b][1]=0.f; acc3[a][b][2]=0.f; acc3[a][b][3]=0.f; }
  float bias[2] = { b3[ng + col], b3[ng + 16 + col] };
  #pragma unroll
  for (int kc = 0; kc < 4; kc++){
    bf16x8 bfr[2];
    #pragma unroll
    for (int nt = 0; nt < 2; nt++)
      bfr[nt] = *(const bf16x8*)(w3t + (size_t)(ng + nt*16 + col)*CM + kc*32 + quad*8);  // L2-resident
    #pragma unroll
    for (int mt = 0; mt < 7; mt++){
      bf16x8 af = *(const bf16x8*)(h2t + (mt*16 + col)*LSH2 + kc*32 + quad*8);
      #pragma unroll
      for (int nt = 0; nt < 2; nt++)
        acc3[mt][nt] = __builtin_amdgcn_mfma_f32_16x16x32_bf16(af, bfr[nt], acc3[mt][nt], 0, 0, 0);
    }
  }
  // ---- epilogue: per n-half repack (reuses tile area), +residual +ReLU ----
  #pragma unroll
  for (int h = 0; h < 2; h++){
    if (nh == h){
      #pragma unroll
      for (int mt = 0; mt < 7; mt++)
        #pragma unroll
        for (int nt = 0; nt < 2; nt++)
          #pragma unroll
          for (int reg = 0; reg < 4; reg++){
            int m = mt*16 + quad*4 + reg;
            pre[m*132 + nb + nt*16 + col] = acc3[mt][nt][reg] + bias[nt];
          }
    }
    __syncthreads();
    for (int i = tid; i < 3584; i += 512){
      int m = i >> 5, f4 = i & 31;
      float4 pv = *(const float4*)(pre + m*132 + f4*4);
      const float* xr = x + (p0+m)*CI + h*128 + f4*4;
      float4 xv = *(const float4*)xr;
      float4 o;
      o.x = fmaxf(pv.x + xv.x, 0.f);
      o.y = fmaxf(pv.y + xv.y, 0.f);
      o.z = fmaxf(pv.z + xv.z, 0.f);
      o.w = fmaxf(pv.w + xv.w, 0.f);
      *(float4*)(out + (p0+m)*CI + h*128 + f4*4) = o;
    }
    __syncthreads();
  }
}

extern "C" void kernel_launch(void* const* d_in, const int* in_sizes, int n_in,
                              void* d_out, int out_size, void* d_ws, size_t ws_size,
                              hipStream_t stream){
  (void)in_sizes; (void)n_in; (void)out_size; (void)ws_size;
  const float* x   = (const float*)d_in[0];
  const float* w1  = (const float*)d_in[1];
  const float* b1  = (const float*)d_in[2];
  const float* g1  = (const float*)d_in[3];
  const float* be1 = (const float*)d_in[4];
  const float* m1  = (const float*)d_in[5];
  const float* v1  = (const float*)d_in[6];
  const float* w2  = (const float*)d_in[7];
  const float* b2  = (const float*)d_in[8];
  const float* g2  = (const float*)d_in[9];
  const float* be2 = (const float*)d_in[10];
  const float* m2  = (const float*)d_in[11];
  const float* v2  = (const float*)d_in[12];
  const float* w3  = (const float*)d_in[13];
  const float* b3  = (const float*)d_in[14];

  char* ws = (char*)d_ws;
  u16* h1  = (u16*)ws;                                  // 25.69 MB
  u16* w1t = (u16*)(ws + (size_t)PIX*CM*2);             // 64 KB
  u16* w3t = w1t + 32768;                               // 64 KB
  float* A1 = (float*)(w3t + 32768);
  float* B1 = A1 + 128;
  float* A2 = B1 + 128;
  float* B2 = A2 + 128;

  kprep<<<128, 256, 0, stream>>>(w1,b1,g1,be1,m1,v1,b2,g2,be2,m2,v2,w3,
                                 w1t,w3t,A1,B1,A2,B2);
  k1<<<PIX/128, 256, 0, stream>>>(x, w1t, A1, B1, h1);
  k23<<<NB*HW/2, 512, 0, stream>>>(h1, w2, A2, B2, w3t, b3, x, (float*)d_out);
}

// Round 6
// 283.957 us; speedup vs baseline: 1.0370x; 1.0370x over previous
//
#include <hip/hip_runtime.h>
#include <stdint.h>

typedef unsigned short u16;
typedef unsigned int   u32;
typedef __attribute__((ext_vector_type(8))) short bf16x8;
typedef __attribute__((ext_vector_type(4))) float f32x4;

#define EPS 1e-3f
#define NB 32
#define HW 56
#define CI 256
#define CM 128
#define PIX (NB*HW*HW)   // 100352

__device__ __forceinline__ float asf(u32 i){ union{u32 u; float f;} t; t.u=i; return t.f; }
__device__ __forceinline__ u16 f2bf(float f){
  union{float f; u32 u;} t; t.f = f;
  u32 x = t.u;
  return (u16)((x + 0x7fffu + ((x>>16)&1u)) >> 16);   // RNE
}

// ---------------- prep: MFMA-fragment-swizzled bf16 weights + BN fold ----------------
// w1s: B-frags for conv1. n-tile t(8) x k-tile kt(8, K=32 each) x lane(64) x 8 bf16
//      lane: col=lane&15, quad=lane>>4 -> n=t*16+col, k=kt*32+quad*8+j
// w3s: B-frags for conv3. n-tile t(16) x k-tile kc(4) x lane(64) x 8 bf16
__global__ __launch_bounds__(256) void kprep(
    const float* __restrict__ w1, const float* __restrict__ b1, const float* __restrict__ g1,
    const float* __restrict__ be1, const float* __restrict__ m1, const float* __restrict__ v1,
    const float* __restrict__ b2, const float* __restrict__ g2,
    const float* __restrict__ be2, const float* __restrict__ m2, const float* __restrict__ v2,
    const float* __restrict__ w3,
    u16* __restrict__ w1s, u16* __restrict__ w3s,
    float* __restrict__ A1, float* __restrict__ B1,
    float* __restrict__ A2, float* __restrict__ B2){
  int i = blockIdx.x*256 + threadIdx.x;
  if (i < 32768){
    { // w1s
      int j = i & 7, lane = (i >> 3) & 63, kt = (i >> 9) & 7, t = i >> 12;
      int col = lane & 15, quad = lane >> 4;
      int n = t*16 + col, k = kt*32 + quad*8 + j;
      w1s[i] = f2bf(w1[k*CM + n]);
    }
    { // w3s
      int j = i & 7, lane = (i >> 3) & 63, kc = (i >> 9) & 3, t = i >> 11;
      int col = lane & 15, quad = lane >> 4;
      int n = t*16 + col, k = kc*32 + quad*8 + j;
      w3s[i] = f2bf(w3[k*CI + n]);
    }
  }
  if (i < 128){
    float s1 = g1[i] * rsqrtf(v1[i] + EPS);
    A1[i] = s1;
    B1[i] = b1[i]*s1 + be1[i] - m1[i]*s1;
    float s2 = g2[i] * rsqrtf(v2[i] + EPS);
    A2[i] = s2;
    B2[i] = b2[i]*s2 + be2[i] - m2[i]*s2;
  }
}

// ---------------- conv1 1x1 256->128 + BN + ReLU (MFMA bf16) ----------------
// 256 thr (4 waves). M=128, N=128, K chunks of 64. B-frags direct from L2 (w1s).
#define K1_LS 72   // A-tile row stride (u16)
__global__ __launch_bounds__(256) void k1(const float* __restrict__ x,
    const u16* __restrict__ w1s, const float* __restrict__ A1v,
    const float* __restrict__ B1v, u16* __restrict__ h1){
  __shared__ __align__(16) char smem[128*136*2];   // 34816 B (A-tile 18432; epilogue 34816)
  u16* As = (u16*)smem;                            // [128][72]
  const int tid  = threadIdx.x;
  const int lane = tid & 63, wv = tid >> 6;
  const int col  = lane & 15, quad = lane >> 4;
  const long p0 = (long)blockIdx.x * 128;
  f32x4 acc[8][2];
  #pragma unroll
  for (int a = 0; a < 8; a++)
    #pragma unroll
    for (int b = 0; b < 2; b++){ acc[a][b][0]=0.f; acc[a][b][1]=0.f; acc[a][b][2]=0.f; acc[a][b][3]=0.f; }
  for (int kc = 0; kc < 4; kc++){
    #pragma unroll
    for (int r = 0; r < 8; r++){
      int idx = r*256 + tid;
      int m = idx >> 4, f4 = idx & 15;
      float4 v = *(const float4*)(x + (p0+m)*CI + kc*64 + f4*4);
      u32 lo = (u32)f2bf(v.x) | ((u32)f2bf(v.y) << 16);
      u32 hi = (u32)f2bf(v.z) | ((u32)f2bf(v.w) << 16);
      *(uint2*)(As + m*K1_LS + f4*4) = make_uint2(lo, hi);
    }
    __syncthreads();
    #pragma unroll
    for (int ks = 0; ks < 2; ks++){
      const int kt = kc*2 + ks;
      bf16x8 bfr[2], af[8];
      #pragma unroll
      for (int nt = 0; nt < 2; nt++)
        bfr[nt] = *(const bf16x8*)(w1s + (size_t)(((wv*2+nt)*8 + kt)*64 + lane)*8);
      #pragma unroll
      for (int mt = 0; mt < 8; mt++)
        af[mt] = *(const bf16x8*)(As + (mt*16 + col)*K1_LS + ks*32 + quad*8);
      #pragma unroll
      for (int mt = 0; mt < 8; mt++)
        #pragma unroll
        for (int nt = 0; nt < 2; nt++)
          acc[mt][nt] = __builtin_amdgcn_mfma_f32_16x16x32_bf16(af[mt], bfr[nt], acc[mt][nt], 0, 0, 0);
    }
    __syncthreads();
  }
  // epilogue: BN + ReLU -> bf16, repack via LDS, vector store
  u16* outw = (u16*)smem;   // [128][136]
  #pragma unroll
  for (int nt = 0; nt < 2; nt++){
    int n = wv*32 + nt*16 + col;
    float a1 = A1v[n], b1v = B1v[n];
    #pragma unroll
    for (int mt = 0; mt < 8; mt++)
      #pragma unroll
      for (int reg = 0; reg < 4; reg++){
        int m = mt*16 + quad*4 + reg;
        outw[m*136 + n] = f2bf(fmaxf(acc[mt][nt][reg]*a1 + b1v, 0.f));
      }
  }
  __syncthreads();
  #pragma unroll
  for (int r = 0; r < 8; r++){
    int idx = r*256 + tid;
    int m = idx >> 4, u4 = idx & 15;
    uint4 v = *(const uint4*)(outw + m*136 + u4*8);
    *(uint4*)(h1 + (p0+m)*CM + u4*8) = v;
  }
}

// ---------------- fused: grouped 3x3 + BN + ReLU + conv3 + bias + residual + ReLU ----------------
// 256 thr (4 waves), one block per output row. h2 band lives only in LDS.
// LDS: tile 44352 + h2t 17408 + wsh 18432 = 80192 B -> 2 blocks/CU.
#define LSH1 132   // h1 tile stride (u16)
#define LSH2 136   // h2 tile stride (u16)
__global__ __launch_bounds__(256) void k23(const u16* __restrict__ h1,
    const float* __restrict__ w2, const float* __restrict__ A2v,
    const float* __restrict__ B2v, const u16* __restrict__ w3s,
    const float* __restrict__ b3, const float* __restrict__ x,
    float* __restrict__ out){
  __shared__ __align__(16) char smem[3*HW*LSH1*2 + 64*LSH2*2 + 4608*4];
  u16*  tile = (u16*)smem;                                // [3][56][132] bf16
  u16*  h2t  = (u16*)(smem + 3*HW*LSH1*2);                // [64][136] bf16
  float* wsh = (float*)(smem + 3*HW*LSH1*2 + 64*LSH2*2);  // [4608] fp32 w2
  float* pre = (float*)smem;                              // [64][132] f32 (reuses tile)

  const int tid = threadIdx.x;
  const int y0 = blockIdx.x % HW;          // row within image
  const long p0 = (long)blockIdx.x * HW;   // first output pixel

  // ---- phase A: stage w2, zero h2t pad rows, stage h1 rows y0-1..y0+1 ----
  for (int i = tid; i < 1152; i += 256)
    ((float4*)wsh)[i] = ((const float4*)w2)[i];
  for (int i = tid; i < 544; i += 256)
    ((u32*)(h2t + 56*LSH2))[i] = 0u;
  #pragma unroll
  for (int r = 0; r < 3; r++){
    const int yy = y0 + r - 1;
    const bool valid = (yy >= 0 && yy < HW);
    const uint4* src = (const uint4*)(h1 + (long)(blockIdx.x - y0 + yy)*HW*CM);
    for (int i = tid; i < 896; i += 256){
      uint4 v = make_uint4(0u,0u,0u,0u);
      if (valid) v = src[i];
      int px = i >> 4, ch = (i & 15)*8;
      u16* d = tile + (r*HW + px)*LSH1 + ch;
      *(uint2*)d     = make_uint2(v.x, v.y);
      *(uint2*)(d+4) = make_uint2(v.z, v.w);
    }
  }
  __syncthreads();

  // ---- phase B: grouped 3x3 conv, fp32 VALU, h2 -> LDS ----
  {
    const int q   = tid >> 6;    // channel-quarter (wave-uniform)
    const int pos = tid & 63;    // pixel, valid < 56
    if (pos < HW){
      int ixo[3]; u32 mk[3];
      #pragma unroll
      for (int kx = 0; kx < 3; kx++){
        int c = pos + kx - 1;
        ixo[kx] = (c < 0 ? 0 : (c > 55 ? 55 : c)) * LSH1;
        mk[kx] = (c >= 0 && c < HW) ? 0xffffffffu : 0u;
      }
      float acc[8][4];
      #pragma unroll
      for (int gi = 0; gi < 8; gi++){
        const int cb = (q*8 + gi)*4;
        float a0=0.f, a1=0.f, a2=0.f, a3=0.f;
        #pragma unroll
        for (int ky = 0; ky < 3; ky++){
          const u16* trow = tile + ky*HW*LSH1 + cb;
          #pragma unroll
          for (int kx = 0; kx < 3; kx++){
            uint2 hv = *(const uint2*)(trow + ixo[kx]);
            u32 hx = hv.x & mk[kx], hy = hv.y & mk[kx];
            float i0 = asf(hx<<16), i1 = asf(hx&0xffff0000u);
            float i2 = asf(hy<<16), i3 = asf(hy&0xffff0000u);
            const float* wp = wsh + ((ky*3+kx)*4)*CM + cb;   // wave-uniform -> broadcast
            float4 w0 = *(const float4*)(wp);
            float4 w1 = *(const float4*)(wp+CM);
            float4 wq2 = *(const float4*)(wp+2*CM);
            float4 wq3 = *(const float4*)(wp+3*CM);
            a0 += i0*w0.x + i1*w1.x + i2*wq2.x + i3*wq3.x;
            a1 += i0*w0.y + i1*w1.y + i2*wq2.y + i3*wq3.y;
            a2 += i0*w0.z + i1*w1.z + i2*wq2.z + i3*wq3.z;
            a3 += i0*w0.w + i1*w1.w + i2*wq2.w + i3*wq3.w;
          }
        }
        acc[gi][0]=a0; acc[gi][1]=a1; acc[gi][2]=a2; acc[gi][3]=a3;
      }
      u16 ov[32];
      #pragma unroll
      for (int gi = 0; gi < 8; gi++)
        #pragma unroll
        for (int co = 0; co < 4; co++){
          int c = q*32 + gi*4 + co;
          ov[gi*4+co] = f2bf(fmaxf(acc[gi][co]*A2v[c] + B2v[c], 0.f));
        }
      u16* op = h2t + pos*LSH2 + q*32;
      #pragma unroll
      for (int v4 = 0; v4 < 4; v4++){
        uint4 pk;
        pk.x = (u32)ov[v4*8+0] | ((u32)ov[v4*8+1]<<16);
        pk.y = (u32)ov[v4*8+2] | ((u32)ov[v4*8+3]<<16);
        pk.z = (u32)ov[v4*8+4] | ((u32)ov[v4*8+5]<<16);
        pk.w = (u32)ov[v4*8+6] | ((u32)ov[v4*8+7]<<16);
        *(uint4*)(op + v4*8) = pk;
      }
    }
  }
  __syncthreads();

  // ---- phase C: conv3 MFMA. M=64 (4 m-tiles, rows 56..63 zero), wave wv owns N=[wv*64, wv*64+64) ----
  const int lane = tid & 63, wv = tid >> 6;
  const int col  = lane & 15, quad = lane >> 4;
  f32x4 acc3[4][4];
  #pragma unroll
  for (int a = 0; a < 4; a++)
    #pragma unroll
    for (int b = 0; b < 4; b++){ acc3[a][b][0]=0.f; acc3[a][b][1]=0.f; acc3[a][b][2]=0.f; acc3[a][b][3]=0.f; }
  float bias[4];
  #pragma unroll
  for (int nt = 0; nt < 4; nt++) bias[nt] = b3[wv*64 + nt*16 + col];
  #pragma unroll
  for (int kc = 0; kc < 4; kc++){
    bf16x8 bfr[4], af[4];
    #pragma unroll
    for (int nt = 0; nt < 4; nt++)
      bfr[nt] = *(const bf16x8*)(w3s + (size_t)(((wv*4+nt)*4 + kc)*64 + lane)*8);  // coalesced, L2
    #pragma unroll
    for (int mt = 0; mt < 4; mt++)
      af[mt] = *(const bf16x8*)(h2t + (mt*16 + col)*LSH2 + kc*32 + quad*8);
    #pragma unroll
    for (int mt = 0; mt < 4; mt++)
      #pragma unroll
      for (int nt = 0; nt < 4; nt++)
        acc3[mt][nt] = __builtin_amdgcn_mfma_f32_16x16x32_bf16(af[mt], bfr[nt], acc3[mt][nt], 0, 0, 0);
  }
  // ---- epilogue: two n-halves through pre (reuses tile region), +residual +ReLU ----
  const int wh = wv >> 1;          // which n-half this wave belongs to
  const int nb = (wv & 1) * 64;    // n base within half
  #pragma unroll
  for (int h = 0; h < 2; h++){
    if (wh == h){
      #pragma unroll
      for (int mt = 0; mt < 4; mt++)
        #pragma unroll
        for (int nt = 0; nt < 4; nt++)
          #pragma unroll
          for (int reg = 0; reg < 4; reg++){
            int m = mt*16 + quad*4 + reg;
            pre[m*132 + nb + nt*16 + col] = acc3[mt][nt][reg] + bias[nt];
          }
    }
    __syncthreads();
    for (int i = tid; i < 1792; i += 256){
      int m = i >> 5, f4 = i & 31;
      float4 pv = *(const float4*)(pre + m*132 + f4*4);
      float4 xv = *(const float4*)(x + (p0+m)*CI + h*128 + f4*4);
      float4 o;
      o.x = fmaxf(pv.x + xv.x, 0.f);
      o.y = fmaxf(pv.y + xv.y, 0.f);
      o.z = fmaxf(pv.z + xv.z, 0.f);
      o.w = fmaxf(pv.w + xv.w, 0.f);
      *(float4*)(out + (p0+m)*CI + h*128 + f4*4) = o;
    }
    __syncthreads();
  }
}

extern "C" void kernel_launch(void* const* d_in, const int* in_sizes, int n_in,
                              void* d_out, int out_size, void* d_ws, size_t ws_size,
                              hipStream_t stream){
  (void)in_sizes; (void)n_in; (void)out_size; (void)ws_size;
  const float* x   = (const float*)d_in[0];
  const float* w1  = (const float*)d_in[1];
  const float* b1  = (const float*)d_in[2];
  const float* g1  = (const float*)d_in[3];
  const float* be1 = (const float*)d_in[4];
  const float* m1  = (const float*)d_in[5];
  const float* v1  = (const float*)d_in[6];
  const float* w2  = (const float*)d_in[7];
  const float* b2  = (const float*)d_in[8];
  const float* g2  = (const float*)d_in[9];
  const float* be2 = (const float*)d_in[10];
  const float* m2  = (const float*)d_in[11];
  const float* v2  = (const float*)d_in[12];
  const float* w3  = (const float*)d_in[13];
  const float* b3  = (const float*)d_in[14];

  char* ws = (char*)d_ws;
  u16* h1  = (u16*)ws;                                  // 25.69 MB
  u16* w1s = (u16*)(ws + (size_t)PIX*CM*2);             // 64 KB
  u16* w3s = w1s + 32768;                               // 64 KB
  float* A1 = (float*)(w3s + 32768);
  float* B1 = A1 + 128;
  float* A2 = B1 + 128;
  float* B2 = A2 + 128;

  kprep<<<128, 256, 0, stream>>>(w1,b1,g1,be1,m1,v1,b2,g2,be2,m2,v2,w3,
                                 w1s,w3s,A1,B1,A2,B2);
  k1<<<PIX/128, 256, 0, stream>>>(x, w1s, A1, B1, h1);
  k23<<<NB*HW, 256, 0, stream>>>(h1, w2, A2, B2, w3s, b3, x, (float*)d_out);
}